// Round 9
// baseline (7010.325 us; speedup 1.0000x reference)
//
#include <hip/hip_runtime.h>

// LSTM B=512, T=512, H=256. Round 9 = r7 structure, weight tier in AGPRs.
// Evidence r1/r7/r8: with 512-thr blocks the allocator hard-caps arch VGPRs at
// 128 (occupancy-remat pass reloads anything above). r6: 256 VGPRs only held at
// 1 wave/SIMD (latency-bound). Fix: the OTHER half of the unified file — AGPRs.
// MFMA B-operands can be AGPRs (cdna4_isa §10); "+a" asm pins put the 128
// weight dwords in a0..a127, VGPR working set stays within the 128 the
// allocator wants. 2 waves/SIMD TLP preserved. Per-use cost: v_accvgpr_read
// copies (~510 cyc/SIMD/step) — cheap vs the 256 KB/step reload it deletes.
// 32 blocks x 512 thr (8 waves). Wave owns 32 gate-cols (nt=g*2+e). Tiers:
//   kt 0..3 AGPR-pinned | kt 4..5 LDS (128 KB) | kt 6..7 L2 stream (128 KB/step).
// MFMA f32_16x16x32_f16: A=h[m=batch=l16][k], B=W[k][n=col=l16], D[m=quad*4+r][n].
// Weights prescaled by -log2e (i,f,o) / +2log2e (g) => nonlinearity is exp2-only.

typedef _Float16 half8 __attribute__((ext_vector_type(8)));
typedef float f32x4 __attribute__((ext_vector_type(4)));
typedef float f32x2 __attribute__((ext_vector_type(2)));

constexpr int kT = 512;
constexpr int kHP = 272;   // h_lds row stride (halves), 544 B
constexpr float kLog2e = 1.44269504088896340736f;

// ws layout, half8 units (16 B):
//   REG  [0,16384):     f = w*32 + nt*4 + kt          (kt 0..3)
//   LDSW [16384,24576): f = w*16 + nt*2 + (kt-4)      (kt 4..5)
//   STRM [24576,32768): f = w*16 + nt*2 + (kt-6)      (kt 6..7)
// element: nt=g*2+e, col R = g*256 + w*32 + 2*(lane&15) + e, k = kt*32 + (lane>>4)*8 + j
__global__ void prep_weights(const float* __restrict__ W_hh, _Float16* __restrict__ ws)
{
    int gid = blockIdx.x * blockDim.x + threadIdx.x;  // 0..32767
    int lane = gid & 63;
    int w, nt, kt;
    if (gid < 16384) {
        int f = gid >> 6;
        kt = f & 3; nt = (f >> 2) & 7; w = f >> 5;
    } else if (gid < 24576) {
        int f = (gid - 16384) >> 6;
        kt = 4 + (f & 1); nt = (f >> 1) & 7; w = f >> 4;
    } else {
        int f = (gid - 24576) >> 6;
        kt = 6 + (f & 1); nt = (f >> 1) & 7; w = f >> 4;
    }
    int g = nt >> 1, e = nt & 1;
    int r = g * 256 + w * 32 + 2 * (lane & 15) + e;
    int k = kt * 32 + (lane >> 4) * 8;
    float s = (g == 2) ? 2.0f * kLog2e : -kLog2e;
    const float* src = W_hh + r * 256 + k;
    half8 v;
    #pragma unroll
    for (int j = 0; j < 8; ++j) v[j] = (_Float16)(src[j] * s);
    reinterpret_cast<half8*>(ws)[gid] = v;
}

__device__ __forceinline__ f32x4 mfma16(half8 a, half8 b, f32x4 c) {
    return __builtin_amdgcn_mfma_f32_16x16x32_f16(a, b, c, 0, 0, 0);
}
__device__ __forceinline__ f32x2 unpack2(unsigned int u) {
    union { unsigned int u; _Float16 h[2]; } cv; cv.u = u;
    f32x2 r; r.x = (float)cv.h[0]; r.y = (float)cv.h[1]; return r;
}

__global__ __launch_bounds__(512, 2)
void lstm_main(const float* __restrict__ ts,
               const float* __restrict__ W_ih,
               const float* __restrict__ b_ih,
               const float* __restrict__ b_hh,
               const float* __restrict__ W_out,
               const float* __restrict__ b_out,
               const _Float16* __restrict__ wfrag,
               float* __restrict__ out)
{
    __shared__ __align__(16) _Float16 wlds[65536];        // 128 KB (kt 4..5)
    __shared__ __align__(16) _Float16 h_lds[2][16][kHP];  // 17 KB
    __shared__ float red[8][16];

    const int tid  = threadIdx.x;
    const int w    = tid >> 6;       // wave 0..7
    const int lane = tid & 63;
    const int l16  = lane & 15;
    const int quad = lane >> 4;
    const int b0   = blockIdx.x * 16;

    const half8* wf8 = reinterpret_cast<const half8*>(wfrag);
    half8* wlds8 = reinterpret_cast<half8*>(wlds);

    // stage LDS weight tier (one-time)
    for (int i = tid; i < 8192; i += 512) wlds8[i] = wf8[16384 + i];
    // zero h parity-1 buffer (t=0 reads parity 1)
    for (int i = tid; i < 16 * kHP; i += 512)
        (&h_lds[1][0][0])[i] = (_Float16)0.0f;

    // ---- AGPR-PINNED register tier: 32 frags x 4 dwords = 128 AGPRs/lane ----
    unsigned int wr_[32][4];
    {
        const uint4* wsrc = reinterpret_cast<const uint4*>(wfrag);
        #pragma unroll
        for (int i = 0; i < 32; ++i) {
            uint4 v = wsrc[(w * 32 + i) * 64 + lane];
            wr_[i][0] = v.x; wr_[i][1] = v.y; wr_[i][2] = v.z; wr_[i][3] = v.w;
            asm volatile("" : "+a"(wr_[i][0]), "+a"(wr_[i][1]), "+a"(wr_[i][2]), "+a"(wr_[i][3]));
        }
    }

    // per-col scalars packed fp16 {wih*s, bias*s} (col = w*32 + 2*l16 + e, nt=g*2+e)
    unsigned int wb16[8];
    #pragma unroll
    for (int nt = 0; nt < 8; ++nt) {
        int g = nt >> 1, e = nt & 1;
        int R = g * 256 + w * 32 + 2 * l16 + e;
        float s = (g == 2) ? 2.0f * kLog2e : -kLog2e;
        union { unsigned int u; _Float16 h[2]; } cv;
        cv.h[0] = (_Float16)(W_ih[R] * s);
        cv.h[1] = (_Float16)((b_ih[R] + b_hh[R]) * s);
        wb16[nt] = cv.u;
    }

    const half8* sps = wf8 + 24576 + w * 1024 + lane;   // STRM: frag (nt,j) at sps[(nt*2+j)*64]

    float cst[8] = {0,0,0,0,0,0,0,0};
    float oacc[4] = {0.f, 0.f, 0.f, 0.f};

    __syncthreads();

    for (int t = 0; t < kT; ++t) {
        const int rp = (t + 1) & 1, wp = t & 1;

        // in-loop re-pin: weights must be AGPR-resident here every iteration.
        // AGPR file is outside the allocator's 128-VGPR occupancy target, so
        // residency is cheap to honor (no remat source, spilling = 128 copies).
        #pragma unroll
        for (int i = 0; i < 32; ++i)
            asm volatile("" : "+a"(wr_[i][0]), "+a"(wr_[i][1]), "+a"(wr_[i][2]), "+a"(wr_[i][3]));

        // A fragments (h) from LDS
        half8 a[8];
        #pragma unroll
        for (int kt = 0; kt < 8; ++kt)
            a[kt] = *reinterpret_cast<const half8*>(&h_lds[rp][l16][kt * 32 + quad * 8]);

        float tsv[4];
        #pragma unroll
        for (int r = 0; r < 4; ++r) tsv[r] = ts[(b0 + quad * 4 + r) * kT + t];
        f32x2 wo = *reinterpret_cast<const f32x2*>(&W_out[t * 256 + w * 32 + 2 * l16]);

        float hv0[4];
        #pragma unroll
        for (int e = 0; e < 2; ++e) {
            // stream tier loads for this e: nt = g*2+e, kt 6..7 (issued first, consumed last)
            half8 s6[4], s7[4];
            #pragma unroll
            for (int g = 0; g < 4; ++g) {
                int nt = g * 2 + e;
                s6[g] = sps[(nt * 2 + 0) * 64];
                s7[g] = sps[(nt * 2 + 1) * 64];
            }
            f32x4 gacc[4];
            #pragma unroll
            for (int g = 0; g < 4; ++g) { f32x4 z = {0.f,0.f,0.f,0.f}; gacc[g] = z; }
            // AGPR tier (kt-outer => 4 independent chains; per-use accvgpr_read)
            #pragma unroll
            for (int kt = 0; kt < 4; ++kt)
                #pragma unroll
                for (int g = 0; g < 4; ++g) {
                    int fi = (g * 2 + e) * 4 + kt;
                    half8 wv = __builtin_bit_cast(half8,
                        make_uint4(wr_[fi][0], wr_[fi][1], wr_[fi][2], wr_[fi][3]));
                    gacc[g] = mfma16(a[kt], wv, gacc[g]);
                }
            // LDS tier
            #pragma unroll
            for (int kk = 0; kk < 2; ++kk)
                #pragma unroll
                for (int g = 0; g < 4; ++g) {
                    int nt = g * 2 + e;
                    half8 lw = wlds8[(w * 16 + nt * 2 + kk) * 64 + lane];
                    gacc[g] = mfma16(a[4 + kk], lw, gacc[g]);
                }
            // stream tier
            #pragma unroll
            for (int g = 0; g < 4; ++g) gacc[g] = mfma16(a[6], s6[g], gacc[g]);
            #pragma unroll
            for (int g = 0; g < 4; ++g) gacc[g] = mfma16(a[7], s7[g], gacc[g]);

            // nonlinearity: lane owns (batch = quad*4+r, col = w*32 + 2*l16 + e)
            f32x2 ib[4];
            #pragma unroll
            for (int g = 0; g < 4; ++g) ib[g] = unpack2(wb16[g * 2 + e]);
            #pragma unroll
            for (int r = 0; r < 4; ++r) {
                float gi = gacc[0][r] + (tsv[r] * ib[0].x + ib[0].y);
                float gf = gacc[1][r] + (tsv[r] * ib[1].x + ib[1].y);
                float gg = gacc[2][r] + (tsv[r] * ib[2].x + ib[2].y);
                float go = gacc[3][r] + (tsv[r] * ib[3].x + ib[3].y);
                float I = __builtin_amdgcn_rcpf(1.0f + __builtin_amdgcn_exp2f(gi));
                float F = __builtin_amdgcn_rcpf(1.0f + __builtin_amdgcn_exp2f(gf));
                float G = 1.0f - 2.0f * __builtin_amdgcn_rcpf(1.0f + __builtin_amdgcn_exp2f(gg));
                float O = __builtin_amdgcn_rcpf(1.0f + __builtin_amdgcn_exp2f(go));
                float c = F * cst[e * 4 + r] + I * G;
                cst[e * 4 + r] = c;
                float tc = 1.0f - 2.0f * __builtin_amdgcn_rcpf(
                               1.0f + __builtin_amdgcn_exp2f(2.0f * kLog2e * c));
                float hv = O * tc;
                oacc[r] += hv * (e ? wo.y : wo.x);
                if (e == 0) hv0[r] = hv;
                else {
                    union { unsigned int u; _Float16 h[2]; } hp;
                    hp.h[0] = (_Float16)hv0[r];
                    hp.h[1] = (_Float16)hv;
                    *reinterpret_cast<unsigned int*>(
                        &h_lds[wp][quad * 4 + r][w * 32 + 2 * l16]) = hp.u;
                }
            }
        }
        __syncthreads();
    }

    // reduce oacc over l16 lanes (cols), then waves
    #pragma unroll
    for (int r = 0; r < 4; ++r) {
        float v = oacc[r];
        v += __shfl_xor(v, 1, 64);
        v += __shfl_xor(v, 2, 64);
        v += __shfl_xor(v, 4, 64);
        v += __shfl_xor(v, 8, 64);
        oacc[r] = v;
    }
    if (l16 == 0) {
        #pragma unroll
        for (int r = 0; r < 4; ++r) red[w][quad * 4 + r] = oacc[r];
    }
    __syncthreads();
    if (tid < 16) {
        float s = b_out[0];
        #pragma unroll
        for (int ww = 0; ww < 8; ++ww) s += red[ww][tid];
        out[b0 + tid] = s;
    }
}

extern "C" void kernel_launch(void* const* d_in, const int* in_sizes, int n_in,
                              void* d_out, int out_size, void* d_ws, size_t ws_size,
                              hipStream_t stream) {
    const float* ts    = (const float*)d_in[0];
    const float* W_ih  = (const float*)d_in[1];
    const float* W_hh  = (const float*)d_in[2];
    const float* b_ih  = (const float*)d_in[3];
    const float* b_hh  = (const float*)d_in[4];
    const float* W_out = (const float*)d_in[5];
    const float* b_out = (const float*)d_in[6];
    _Float16* wfrag = (_Float16*)d_ws;   // 512 KB of fragments

    prep_weights<<<128, 256, 0, stream>>>(W_hh, wfrag);
    lstm_main<<<32, 512, 0, stream>>>(ts, W_ih, b_ih, b_hh, W_out, b_out,
                                      wfrag, (float*)d_out);
}

// Round 10
// 1603.319 us; speedup vs baseline: 4.3724x; 4.3724x over previous
//
#include <hip/hip_runtime.h>

// LSTM B=512, T=512, H=256. Round 10: H-split-by-4, all-LDS weights, LLC exchange.
// r4-r9 verdict: >128 persistent regs/lane is unobtainable (remat/spill/copy-churn),
// and any weight byte outside LDS pays the 64 B/cyc/CU VMEM straw. Fix: shrink the
// per-CU weight footprint. 128 blocks x 512 thr; group bid>>2 owns 16 batches;
// sub=bid&3 owns h-outputs [64*sub,64*sub+64) -> W slice 4g x 64col x 256K fp16
// = 128 KB, fully LDS-resident. Per step: block computes its h-quarter, publishes
// 2 KB to LLC (relaxed agent atomics, double-buffered by step parity), copies 3
// partner quarters. Flags monotonic; ordering = __syncthreads' vmcnt(0) drain
// before s_barrier (no acquire/release -> no buffer_wbl2 storms, r5's killer).
// Safety: at my step t I saw flag[p]>=t => p finished t-1 => consumed tile t-2,
// which is exactly the parity slot I overwrite at step t. All 128 blocks fit
// co-resident (1/CU by LDS), so spins always make progress.
// Waves: w<4 (c=w): kt 0..3 + nonlinearity; w>=4 (c=w-4): kt 4..7, partials via
// padded LDS. MFMA f32_16x16x32_f16: A=h[m=batch=l16][k], B=W[k][n=l16],
// D[m=quad*4+r][n=l16]. Weights prescaled by -log2e (i,f,o) / +2log2e (g).

typedef _Float16 half8 __attribute__((ext_vector_type(8)));
typedef float f32x4 __attribute__((ext_vector_type(4)));

constexpr int kT = 512;
constexpr int kHF = 264;   // h_full row stride (halves): 132 dw = 4 mod 32 -> 2-way b128 (free)
constexpr float kLog2e = 1.44269504088896340736f;

#define ATL(p)    __hip_atomic_load((p), __ATOMIC_RELAXED, __HIP_MEMORY_SCOPE_AGENT)
#define ATS(p, v) __hip_atomic_store((p), (v), __ATOMIC_RELAXED, __HIP_MEMORY_SCOPE_AGENT)

// ws layout (bytes):
//   [0, 524288)        weight fragments fp16: frag (sub,c,g,kt) at half8 idx
//                      (sub*128 + (c*4+g)*8 + kt)*64 + lane
//   [524288, 1048576)  gbuf: tile(bid,par) 2 KB at + (bid*2+par)*2048; [hl][m] u16
//   [1048576, 1049088) flags int[128]
//   [1049088, 1057280) pbuf float[128][16]
__global__ void prep_weights(const float* __restrict__ W_hh, _Float16* __restrict__ ws)
{
    int gid = blockIdx.x * blockDim.x + threadIdx.x;  // 0..32767, one half8 each
    int lane = gid & 63;
    int f = (gid >> 6) & 127;
    int sub = gid >> 13;
    int kt = f & 7, g = (f >> 3) & 3, c = f >> 5;
    int R = g * 256 + sub * 64 + c * 16 + (lane & 15);
    int k = kt * 32 + (lane >> 4) * 8;
    float s = (g == 2) ? 2.0f * kLog2e : -kLog2e;
    const float* src = W_hh + R * 256 + k;
    half8 v;
    #pragma unroll
    for (int j = 0; j < 8; ++j) v[j] = (_Float16)(src[j] * s);
    reinterpret_cast<half8*>(ws)[gid] = v;
}

__device__ __forceinline__ f32x4 mfma16(half8 a, half8 b, f32x4 c) {
    return __builtin_amdgcn_mfma_f32_16x16x32_f16(a, b, c, 0, 0, 0);
}

__global__ __launch_bounds__(512, 2)
void lstm_main(const float* __restrict__ ts,
               const float* __restrict__ W_ih,
               const float* __restrict__ b_ih,
               const float* __restrict__ b_hh,
               const float* __restrict__ W_out,
               const _Float16* __restrict__ wfrag,
               unsigned short* __restrict__ gb,
               int* __restrict__ flags,
               float* __restrict__ pbuf)
{
    __shared__ __align__(16) _Float16 wlds[65536];        // 128 KB weights
    __shared__ __align__(16) _Float16 h_full[16][kHF];    // 8448 B (single-buffered)
    __shared__ __align__(16) float pacc1[4][4][16][20];   // 20480 B (kh=1 partials, padded)
    __shared__ float red[4][16];

    const int tid  = threadIdx.x;
    const int w    = tid >> 6;
    const int lane = tid & 63;
    const int l16  = lane & 15;
    const int quad = lane >> 4;
    const int bid  = blockIdx.x;
    const int sub  = bid & 3;
    const int grp  = bid >> 2;
    const int b0   = grp * 16;
    const int c    = w & 3;       // column-group 0..3
    const int kh   = w >> 2;      // K-half 0..1

    const half8* wf8 = reinterpret_cast<const half8*>(wfrag) + sub * 8192;
    half8* wl8 = reinterpret_cast<half8*>(wlds);

    // stage weights (one-time, 128 KB)
    for (int i = tid; i < 8192; i += 512) wl8[i] = wf8[i];
    // zero h_full (h_{-1} = 0)
    for (int i = tid; i < 16 * kHF; i += 512) (&h_full[0][0])[i] = (_Float16)0.0f;

    // per-col scalars (nonlin waves only), prescaled
    float wih[4], bias[4];
    if (w < 4) {
        #pragma unroll
        for (int g = 0; g < 4; ++g) {
            int R = g * 256 + sub * 64 + c * 16 + l16;
            float s = (g == 2) ? 2.0f * kLog2e : -kLog2e;
            wih[g]  = W_ih[R] * s;
            bias[g] = (b_ih[R] + b_hh[R]) * s;
        }
    }

    // LLC exchange pointers
    unsigned short* myt[2] = { gb + (bid * 2 + 0) * 1024, gb + (bid * 2 + 1) * 1024 };
    const int cs   = tid >> 7;                 // 0: non-copier; 1..3: partner offset
    const int psub = (sub + cs) & 3;
    const int pbid = (grp << 2) | psub;
    const unsigned long long* ptile[2] = {
        (const unsigned long long*)(gb + (pbid * 2 + 0) * 1024),
        (const unsigned long long*)(gb + (pbid * 2 + 1) * 1024) };

    float cst[4]  = {0.f, 0.f, 0.f, 0.f};
    float oacc[4] = {0.f, 0.f, 0.f, 0.f};

    __syncthreads();

    for (int t = 0; t < kT; ++t) {
        const int wp = t & 1;          // parity I write (h_t)
        const int rp = (t + 1) & 1;    // parity holding partner h_{t-1}

        // ---- fetch partner quarters (copier threads: tid 128..511) ----
        if (cs >= 1) {
            if (t > 0) {
                while (ATL(&flags[pbid]) < t) __builtin_amdgcn_s_sleep(1);
                asm volatile("" ::: "memory");
            }
            // tile layout [hl][m] u16; thread copies 16 B = 2 u64 (one hl, 8 m)
            int i0 = (tid & 127) * 2;                  // u64 index
            unsigned long long d0 = ATL(ptile[rp] + i0);
            unsigned long long d1 = ATL(ptile[rp] + i0 + 1);
            int hl = i0 >> 2;
            int m0 = (i0 & 3) * 4;                     // 0 or 8
            union { unsigned long long u; unsigned short s[4]; } u0, u1;
            u0.u = d0; u1.u = d1;
            #pragma unroll
            for (int j = 0; j < 4; ++j) {
                reinterpret_cast<unsigned short*>(&h_full[m0 + j][psub * 64 + hl])[0] = u0.s[j];
                reinterpret_cast<unsigned short*>(&h_full[m0 + 4 + j][psub * 64 + hl])[0] = u1.s[j];
            }
        }
        __syncthreads();

        // ---- MFMA: wave (c,kh) does 4 g-tiles x its 4 K-slices ----
        half8 a[4];
        #pragma unroll
        for (int j = 0; j < 4; ++j)
            a[j] = *reinterpret_cast<const half8*>(&h_full[l16][(kh * 4 + j) * 32 + quad * 8]);
        f32x4 gacc[4];
        #pragma unroll
        for (int g = 0; g < 4; ++g) { f32x4 z = {0.f, 0.f, 0.f, 0.f}; gacc[g] = z; }
        #pragma unroll
        for (int j = 0; j < 4; ++j)
            #pragma unroll
            for (int g = 0; g < 4; ++g)
                gacc[g] = mfma16(a[j], wl8[(((c * 4 + g) * 8) + kh * 4 + j) * 64 + lane], gacc[g]);

        if (w >= 4) {   // publish kh=1 partials
            #pragma unroll
            for (int g = 0; g < 4; ++g)
                *reinterpret_cast<f32x4*>(&pacc1[c][g][l16][quad * 4]) = gacc[g];
        }
        __syncthreads();

        // ---- nonlinearity (waves 0..3): lane owns col hl=c*16+l16, batches quad*4+r ----
        if (w < 4) {
            f32x4 p1[4];
            #pragma unroll
            for (int g = 0; g < 4; ++g)
                p1[g] = *reinterpret_cast<const f32x4*>(&pacc1[c][g][l16][quad * 4]);
            float tsv[4];
            #pragma unroll
            for (int r = 0; r < 4; ++r) tsv[r] = ts[(b0 + quad * 4 + r) * kT + t];
            const int hl = c * 16 + l16;
            const int hk = sub * 64 + hl;
            float wo = W_out[t * 256 + hk];
            union { unsigned long long u; unsigned short s[4]; } hp;
            #pragma unroll
            for (int r = 0; r < 4; ++r) {
                float gi = gacc[0][r] + p1[0][r] + (tsv[r] * wih[0] + bias[0]);
                float gf = gacc[1][r] + p1[1][r] + (tsv[r] * wih[1] + bias[1]);
                float gg = gacc[2][r] + p1[2][r] + (tsv[r] * wih[2] + bias[2]);
                float go = gacc[3][r] + p1[3][r] + (tsv[r] * wih[3] + bias[3]);
                float I = __builtin_amdgcn_rcpf(1.0f + __builtin_amdgcn_exp2f(gi));
                float F = __builtin_amdgcn_rcpf(1.0f + __builtin_amdgcn_exp2f(gf));
                float G = 1.0f - 2.0f * __builtin_amdgcn_rcpf(1.0f + __builtin_amdgcn_exp2f(gg));
                float O = __builtin_amdgcn_rcpf(1.0f + __builtin_amdgcn_exp2f(go));
                float cn = F * cst[r] + I * G;
                cst[r] = cn;
                float tc = 1.0f - 2.0f * __builtin_amdgcn_rcpf(
                               1.0f + __builtin_amdgcn_exp2f(2.0f * kLog2e * cn));
                float hv = O * tc;
                oacc[r] += hv * wo;
                _Float16 h16 = (_Float16)hv;
                hp.s[r] = __builtin_bit_cast(unsigned short, h16);
                h_full[quad * 4 + r][hk] = h16;    // own LDS copy
            }
            // LLC copy: tile[hl][m], lane's 4 m's contiguous -> one u64 atomic store
            ATS((unsigned long long*)myt[wp] + (hl * 4 + quad), hp.u);
        }
        __syncthreads();   // drains each wave's vmcnt before s_barrier -> stores at LLC
        if (tid == 0) ATS(&flags[bid], t + 1);
    }

    // ---- output partials: sum over cols (l16 lanes), then c-groups ----
    if (w < 4) {
        #pragma unroll
        for (int r = 0; r < 4; ++r) {
            float v = oacc[r];
            v += __shfl_xor(v, 1, 64);
            v += __shfl_xor(v, 2, 64);
            v += __shfl_xor(v, 4, 64);
            v += __shfl_xor(v, 8, 64);
            oacc[r] = v;
        }
        if (l16 == 0) {
            #pragma unroll
            for (int r = 0; r < 4; ++r) red[c][quad * 4 + r] = oacc[r];
        }
    }
    __syncthreads();
    if (tid < 16) {
        float s = 0.f;
        #pragma unroll
        for (int cc = 0; cc < 4; ++cc) s += red[cc][tid];
        pbuf[bid * 16 + tid] = s;   // plain store; next kernel on same stream sees it
    }
}

__global__ void finalize(const float* __restrict__ pbuf,
                         const float* __restrict__ b_out,
                         float* __restrict__ out)
{
    int b = blockIdx.x * blockDim.x + threadIdx.x;   // 0..511
    int grp = b >> 4, m = b & 15;
    float s = b_out[0];
    #pragma unroll
    for (int s4 = 0; s4 < 4; ++s4) s += pbuf[((grp * 4 + s4) * 16) + m];
    out[b] = s;
}

extern "C" void kernel_launch(void* const* d_in, const int* in_sizes, int n_in,
                              void* d_out, int out_size, void* d_ws, size_t ws_size,
                              hipStream_t stream) {
    const float* ts    = (const float*)d_in[0];
    const float* W_ih  = (const float*)d_in[1];
    const float* W_hh  = (const float*)d_in[2];
    const float* b_ih  = (const float*)d_in[3];
    const float* b_hh  = (const float*)d_in[4];
    const float* W_out = (const float*)d_in[5];
    const float* b_out = (const float*)d_in[6];

    char* wsb = (char*)d_ws;
    _Float16*       wfrag = (_Float16*)wsb;
    unsigned short* gb    = (unsigned short*)(wsb + 524288);
    int*            flags = (int*)(wsb + 1048576);
    float*          pbuf  = (float*)(wsb + 1049088);

    // zero gbuf + flags + pbuf (ws is re-poisoned to 0xAA before every launch)
    hipMemsetAsync(wsb + 524288, 0, 524288 + 512 + 8192, stream);
    prep_weights<<<128, 256, 0, stream>>>(W_hh, wfrag);
    lstm_main<<<128, 512, 0, stream>>>(ts, W_ih, b_ih, b_hh, W_out,
                                       wfrag, gb, flags, pbuf);
    finalize<<<1, 512, 0, stream>>>(pbuf, b_out, (float*)d_out);
}